// Round 2
// 219.078 us; speedup vs baseline: 1.0365x; 1.0365x over previous
//
#include <hip/hip_runtime.h>

// WindowAttention (Swin-3D) on MI355X / gfx950.
// R15 = R14 with the cvt_pkrtz type fix (bit_cast to uint) and P stored via
// 2x ds_write_b64 (uint2) instead of 4x b32 — bank-uniform (4 dwords/bank).
// attn rework recap: QK^T computed transposed (S^T = mfma(K,Q)) so each lane
// holds consecutive keys for its own query column; mask is key-bit-packed in
// 12 registers/lane; PV computed as O^T = mfma(V^T, P) -> epilogue is 2x v4h
// stores with per-lane uniform 1/rsum. K/V/P LDS tiles use exact strides +
// 16B-block XOR swizzles: LDS 78336 -> 53248 B => 3 blocks/CU, 768 = 3*256
// grid. XCD-chunked block swizzle keeps each XCD on 1.5 bias head-slices.

#define DIMD 384
#define NHH 12
#define HEADD 32
#define LL 343
#define NWW 64
#define NTOK (NWW * LL)            // 21952
#define MPT 176                    // m tiles (128 each)
#define MP (MPT * 128)             // 22528
#define LP 352                     // L padded to 22*16
#define QT 22
#define MW 12                      // mask words per query row (11 used)
#define CSS 136                    // qkv epilogue LDS stride (f16)
#define SCALE_ 0.17677669529663687f
#define LOG2E_ 1.4426950408889634f
#define NEGBIG_ (-1.0e4f)

typedef _Float16 f16;
typedef _Float16 v8h __attribute__((ext_vector_type(8)));
typedef _Float16 v4h __attribute__((ext_vector_type(4)));
typedef float v4f __attribute__((ext_vector_type(4)));

__device__ __forceinline__ void async_cp16(const void* g, void* l) {
    __builtin_amdgcn_global_load_lds(
        (const __attribute__((address_space(1))) void*)g,
        (__attribute__((address_space(3))) void*)l, 16, 0, 0);
}

__device__ __forceinline__ unsigned int pk2(float a, float b) {
    return __builtin_bit_cast(unsigned int, __builtin_amdgcn_cvt_pkrtz(a, b));
}

// ---- workspace layout (bytes) ----
constexpr size_t HBUF = (size_t)NHH * MP * HEADD * 2;          // per q/k/v
constexpr size_t OFF_Q    = 0;
constexpr size_t OFF_K    = OFF_Q  + HBUF;
constexpr size_t OFF_V    = OFF_K  + HBUF;
constexpr size_t OFF_AO   = OFF_V  + HBUF;                     // f16 [MP][384]; xh then AO
constexpr size_t OFF_BT   = OFF_AO + (size_t)MP * DIMD * 2;    // f32 biasT (NH,88,352,4) *log2e, key-major
constexpr size_t OFF_WT   = OFF_BT + (size_t)NHH * LP * LP * 4;
constexpr size_t OFF_PWT  = OFF_WT + (size_t)3 * DIMD * DIMD * 2;
constexpr size_t OFF_MTB  = OFF_PWT + (size_t)DIMD * DIMD * 2; // uint (NW, 352 queries, 12 key-words)

// attn LDS: Ks [352][32] + Vts [32][352] + P 8x[16][32], all swizzled, f16
constexpr int SMEM_ATTN = (LP * 32 + 32 * LP + 8 * 16 * 32) * 2;   // 53248

// ---------------- fused prep ----------------
#define S0 (NTOK * DIMD / 4)
#define S1 (3 * DIMD * DIMD)
#define S2 (DIMD * DIMD)
#define S3 (NHH * LP * LP)
#define S4 (NWW * MW * LP)
#define SPREP (S0 + S1 + S2 + S3 + S4)

__global__ __launch_bounds__(256) void prep_all(
    const float* __restrict__ x, f16* __restrict__ xh,
    const float* __restrict__ qkv_w, f16* __restrict__ wt,
    const float* __restrict__ proj_w, f16* __restrict__ pwt,
    const float* __restrict__ table, const int* __restrict__ rel, float* __restrict__ btf,
    const int* __restrict__ mask, unsigned int* __restrict__ mtb) {
    int t = blockIdx.x * 256 + threadIdx.x;
    if (t < S0) {
        float4 v = *(const float4*)(x + (size_t)t * 4);
        v4h o; o[0] = (f16)v.x; o[1] = (f16)v.y; o[2] = (f16)v.z; o[3] = (f16)v.w;
        *(v4h*)(xh + (size_t)t * 4) = o;
    } else if (t < S0 + S1) {
        int e = t - S0;
        int n = e / DIMD, k = e % DIMD;          // wt[n][k] = qkv_w[k][n]
        wt[e] = (f16)qkv_w[(size_t)k * (3 * DIMD) + n];
    } else if (t < S0 + S1 + S2) {
        int e = t - S0 - S1;
        int n = e / DIMD, k = e % DIMD;
        pwt[e] = (f16)proj_w[(size_t)k * DIMD + n];
    } else if (t < S0 + S1 + S2 + S3) {
        // biasT[h][kq][q][e2] = bias(h, query=q, key=kq*4+e2)*log2e, pads -> -1e4
        int e = t - S0 - S1 - S2;
        int h = e / (LP * LP), rem = e % (LP * LP);
        int kq = rem / (LP * 4);
        int rem2 = rem % (LP * 4);
        int col = rem2 >> 2, e2 = rem2 & 3;      // col = query
        int key = kq * 4 + e2;
        float v = NEGBIG_;
        if (col < LL && key < LL) v = table[(size_t)rel[col * LL + key] * NHH + h] * LOG2E_;
        btf[e] = v;
    } else if (t < SPREP) {
        // mtb[n][q][kw]: bit b = mask[n][query q][key kw*32+b]
        int e = t - S0 - S1 - S2 - S3;
        int n = e / (MW * LP), rem = e % (MW * LP);
        int q = rem / MW, kw = rem % MW;
        unsigned int wd = 0;
        if (q < LL && kw < 11) {
            int kbase = kw * 32;
            int kmax = LL - kbase; if (kmax > 32) kmax = 32;
            const int* mrow = mask + ((size_t)n * LL + q) * LL + kbase;
#pragma unroll 4
            for (int b = 0; b < kmax; ++b)
                if (mrow[b]) wd |= (1u << b);
        }
        mtb[((size_t)n * LP + q) * MW + kw] = wd;
    }
}

// ---------------- QKV GEMM (128x128, async staging, XCD swizzle, LDS epilogue) ----------------
__global__ __launch_bounds__(256) void qkv_gemm(
    const f16* __restrict__ xh, const f16* __restrict__ wt,
    f16* __restrict__ qb, f16* __restrict__ kb, f16* __restrict__ vb) {
    __shared__ f16 ABs[8192];
    f16* As = ABs;
    f16* Bs = ABs + 4096;
    const int lin = blockIdx.x;
    const int m0 = ((lin / 72) * 8 + (lin & 7)) * 128;
    const int n0 = ((lin >> 3) % 9) * 128;
    const int tid = threadIdx.x;
    const int wave = tid >> 6, lane = tid & 63;
    const int quad = lane >> 4, l15 = lane & 15;
    const int wm = (wave >> 1) * 64, wn = (wave & 1) * 64;
    const int srow = (lane >> 2);
    const int scol = (lane & 3) * 8;
    const f16* ga0 = xh + (size_t)(m0 + wave * 32 + srow) * DIMD + scol;
    const f16* ga1 = xh + (size_t)(m0 + wave * 32 + 16 + srow) * DIMD + scol;
    const f16* gb0 = wt + (size_t)(n0 + wave * 32 + srow) * DIMD + scol;
    const f16* gb1 = wt + (size_t)(n0 + wave * 32 + 16 + srow) * DIMD + scol;
    f16* la0 = As + (wave * 2) * 512;
    f16* la1 = As + (wave * 2 + 1) * 512;
    f16* lb0 = Bs + (wave * 2) * 512;
    f16* lb1 = Bs + (wave * 2 + 1) * 512;
    v4f acc[4][4] = {};
    for (int k0 = 0; k0 < DIMD; k0 += 32) {
        async_cp16(ga0 + k0, la0);
        async_cp16(ga1 + k0, la1);
        async_cp16(gb0 + k0, lb0);
        async_cp16(gb1 + k0, lb1);
        __syncthreads();
        v8h a[4], b[4];
#pragma unroll
        for (int i = 0; i < 4; ++i) a[i] = *(const v8h*)(As + (wm + i * 16 + l15) * 32 + quad * 8);
#pragma unroll
        for (int j = 0; j < 4; ++j) b[j] = *(const v8h*)(Bs + (wn + j * 16 + l15) * 32 + quad * 8);
#pragma unroll
        for (int i = 0; i < 4; ++i)
#pragma unroll
            for (int j = 0; j < 4; ++j)
                acc[i][j] = __builtin_amdgcn_mfma_f32_16x16x32_f16(a[i], b[j], acc[i][j], 0, 0, 0);
        __syncthreads();
    }
    // epilogue: LDS-transposed coalesced stores into [h][MP][32] layout
    const int t = n0 / DIMD;
    f16* dst = (t == 0) ? qb : (t == 1) ? kb : vb;
    const float sc = (t == 0) ? (SCALE_ * LOG2E_) : 1.0f;
    const int nrel = n0 - t * DIMD;     // 0/128/256 within this third
    f16* Cs = ABs;                      // 32 x CSS f16 = 8704 B (within 16 KB)
    const int rl0 = (wave >> 1) * 16 + quad * 4;
#pragma unroll
    for (int i = 0; i < 4; ++i) {
#pragma unroll
        for (int e = 0; e < 4; ++e)
#pragma unroll
            for (int j = 0; j < 4; ++j)
                Cs[(rl0 + e) * CSS + wn + j * 16 + l15] = (f16)(acc[i][j][e] * sc);
        __syncthreads();
#pragma unroll
        for (int c = 0; c < 2; ++c) {
            int idx = c * 256 + tid;
            int rl = idx >> 4, col8 = (idx & 15) * 8;
            int gm = m0 + ((rl < 16) ? (i * 16 + rl) : (48 + i * 16 + rl));
            if (gm < NTOK) {
                int col = nrel + col8;          // global column within this third
                size_t off = (size_t)(col >> 5) * ((size_t)MP * HEADD)
                           + (col & 31) + (size_t)gm * HEADD;
                *(v8h*)(dst + off) = *(const v8h*)(Cs + rl * CSS + col8);  // 8 f16 = 16B
            }
        }
        __syncthreads();
    }
}

// ---------------- attention (S^T tiles, reg-mask, packed P, 3 blocks/CU) ----------------
__global__ __launch_bounds__(512, 6) void attn_kernel(
    const f16* __restrict__ qb, const f16* __restrict__ kb, const f16* __restrict__ vb,
    const float* __restrict__ biasT, const unsigned int* __restrict__ mtb,
    f16* __restrict__ ao) {
    extern __shared__ char smem[];
    f16* Ks  = (f16*)smem;            // [352 keys][32 ch], 16B-block XOR by (key&3)
    f16* Vts = Ks + LP * 32;          // [32 ch][352 keys], 16B-block XOR by (ch&3)
    f16* Ps  = Vts + 32 * LP;         // 8 waves x [16 q][32 keys], block XOR by ((l15>>1)&3)
    const int bid = blockIdx.x;
    // XCD-chunked swizzle: XCD x owns j2 in [96x, 96x+96) -> 1.5 head slices per XCD L2
    const int j2 = (bid & 7) * 96 + (bid >> 3);
    const int n = j2 & 63, h = j2 >> 6;
    const int tid = threadIdx.x, wave = tid >> 6, lane = tid & 63;
    const int quad = lane >> 4, l15 = lane & 15;
    const size_t slice = ((size_t)h * MP + n * LL) * HEADD;
    const f16* qg = qb + slice;
    const f16* kg = kb + slice;
    const f16* vg = vb + slice;
    // K staging: [key][32ch], swizzled 16B blocks, zero-pad keys >= LL
    for (int i = tid; i < LP * 4; i += 512) {
        int row = i >> 2, c8 = i & 3;
        v8h vv = {};
        if (row < LL) vv = *(const v8h*)(kg + (size_t)i * 8);
        *(v8h*)(Ks + row * 32 + ((c8 ^ (row & 3)) << 3)) = vv;
    }
    // V^T staging: [ch][key], swizzled, zero-pad keys >= LL
    for (int i = tid; i < LP * 8; i += 512) {
        int key = i >> 3, c4 = (i & 7) * 4;
        ushort4 vv = make_ushort4(0, 0, 0, 0);
        if (key < LL) vv = *(const ushort4*)(vg + (size_t)key * HEADD + c4);
        int blk = key >> 3, off = key & 7;
        Vts[(c4 + 0) * LP + ((blk ^ 0) << 3) + off] = *(const f16*)&vv.x;
        Vts[(c4 + 1) * LP + ((blk ^ 1) << 3) + off] = *(const f16*)&vv.y;
        Vts[(c4 + 2) * LP + ((blk ^ 2) << 3) + off] = *(const f16*)&vv.z;
        Vts[(c4 + 3) * LP + ((blk ^ 3) << 3) + off] = *(const f16*)&vv.w;
    }
    __syncthreads();
    f16* Pw = Ps + wave * (16 * 32);
    const float* bh = biasT + (size_t)h * LP * LP;     // [88 key-quads][352 q][4]
    const unsigned int* mg = mtb + (size_t)n * LP * MW;
    const v8h ones = {(f16)1.f, (f16)1.f, (f16)1.f, (f16)1.f,
                      (f16)1.f, (f16)1.f, (f16)1.f, (f16)1.f};
    const int pswz = (l15 >> 1) & 3;
    const int kswz = (quad ^ (l15 & 3)) << 3;
    for (int qt = wave; qt < QT; qt += 8) {
        const int q = qt * 16 + l15;
        v8h af = *(const v8h*)(qg + (size_t)q * HEADD + quad * 8);      // Q[q][ch]
        uint4 mA = *(const uint4*)(mg + q * MW);
        uint4 mB = *(const uint4*)(mg + q * MW + 4);
        uint4 mC = *(const uint4*)(mg + q * MW + 8);
        unsigned int m[12] = {mA.x, mA.y, mA.z, mA.w, mB.x, mB.y, mB.z, mB.w,
                              mC.x, mC.y, mC.z, mC.w};
        const float* bq = bh + (size_t)q * 4;
        v4f cinN[2];
        cinN[0] = *(const v4f*)(bq + (size_t)(quad) * (LP * 4));
        cinN[1] = *(const v4f*)(bq + (size_t)(4 + quad) * (LP * 4));
        v4f o0 = {}, o1 = {}, o2 = {};
#pragma unroll
        for (int ktp = 0; ktp < 11; ++ktp) {
            v4f cin0 = cinN[0], cin1 = cinN[1];
            if (ktp < 10) {   // depth-1 prefetch: overlaps this tile's exp/PV
                cinN[0] = *(const v4f*)(bq + (size_t)((ktp + 1) * 8 + quad) * (LP * 4));
                cinN[1] = *(const v4f*)(bq + (size_t)((ktp + 1) * 8 + 4 + quad) * (LP * 4));
            }
            v8h bf0 = *(const v8h*)(Ks + (ktp * 32 + l15) * 32 + kswz);
            v8h bf1 = *(const v8h*)(Ks + (ktp * 32 + 16 + l15) * 32 + kswz);
            unsigned int mw = m[ktp];
            unsigned int mb0 = mw >> (quad * 4);
            unsigned int mb1 = mw >> (quad * 4 + 16);
#pragma unroll
            for (int e = 0; e < 4; ++e) {
                if ((mb0 >> e) & 1u) cin0[e] = NEGBIG_;
                if ((mb1 >> e) & 1u) cin1[e] = NEGBIG_;
            }
            // S^T tile: rows = keys (quad*4+e), cols = queries (l15)
            v4f s0 = __builtin_amdgcn_mfma_f32_16x16x32_f16(bf0, af, cin0, 0, 0, 0);
            v4f s1 = __builtin_amdgcn_mfma_f32_16x16x32_f16(bf1, af, cin1, 0, 0, 0);
            unsigned int u0 = pk2(__builtin_amdgcn_exp2f(s0[0]), __builtin_amdgcn_exp2f(s0[1]));
            unsigned int u1 = pk2(__builtin_amdgcn_exp2f(s0[2]), __builtin_amdgcn_exp2f(s0[3]));
            unsigned int u2 = pk2(__builtin_amdgcn_exp2f(s1[0]), __builtin_amdgcn_exp2f(s1[1]));
            unsigned int u3 = pk2(__builtin_amdgcn_exp2f(s1[2]), __builtin_amdgcn_exp2f(s1[3]));
            // P[q=l15][key 0..31]: logical block b = half*2 + (quad>>1), XOR pswz
            // b64 stores: 8B contiguous (keys quad*4..+3), bank-uniform (4 dw/bank)
            f16* pr = Pw + l15 * 32 + (quad & 1) * 4;
            *(uint2*)(pr + ((((quad >> 1) + 0) ^ pswz) << 3)) = make_uint2(u0, u1);
            *(uint2*)(pr + ((((quad >> 1) + 2) ^ pswz) << 3)) = make_uint2(u2, u3);
            v8h a = *(const v8h*)(Pw + l15 * 32 + ((quad ^ pswz) << 3));
            int vblk = ((ktp * 4 + quad) ^ (l15 & 3)) << 3;
            v8h w0 = *(const v8h*)(Vts + l15 * LP + vblk);            // V^T rows ch 0..15
            v8h w1 = *(const v8h*)(Vts + (16 + l15) * LP + vblk);     // ch 16..31
            // O^T: rows = ch (quad*4+e), cols = queries (l15)
            o0 = __builtin_amdgcn_mfma_f32_16x16x32_f16(w0, a, o0, 0, 0, 0);
            o1 = __builtin_amdgcn_mfma_f32_16x16x32_f16(w1, a, o1, 0, 0, 0);
            o2 = __builtin_amdgcn_mfma_f32_16x16x32_f16(ones, a, o2, 0, 0, 0);  // rsum[q]
        }
        if (q < LL) {
            float inv = 1.0f / o2[0];          // rsum for this lane's query, uniform in e
            f16* orow = ao + ((size_t)(n * LL + q)) * DIMD + h * HEADD + quad * 4;
            v4h w0, w1;
#pragma unroll
            for (int e = 0; e < 4; ++e) {
                w0[e] = (f16)(o0[e] * inv);
                w1[e] = (f16)(o1[e] * inv);
            }
            *(v4h*)(orow) = w0;
            *(v4h*)(orow + 16) = w1;
        }
    }
}

// ---------------- proj GEMM (128x128, async staging, XCD swizzle) ----------------
__global__ __launch_bounds__(256) void proj_gemm(
    const f16* __restrict__ ao, const f16* __restrict__ pwt,
    const float* __restrict__ pb, float* __restrict__ out) {
    __shared__ f16 As[128 * 32];
    __shared__ f16 Bs[128 * 32];
    const int lin = blockIdx.x;
    const int m0 = ((lin / 24) * 8 + (lin & 7)) * 128;
    const int n0 = ((lin >> 3) % 3) * 128;
    const int tid = threadIdx.x;
    const int wave = tid >> 6, lane = tid & 63;
    const int quad = lane >> 4, l15 = lane & 15;
    const int wm = (wave >> 1) * 64, wn = (wave & 1) * 64;
    const int srow = (lane >> 2);
    const int scol = (lane & 3) * 8;
    const f16* ga0 = ao + (size_t)(m0 + wave * 32 + srow) * DIMD + scol;
    const f16* ga1 = ao + (size_t)(m0 + wave * 32 + 16 + srow) * DIMD + scol;
    const f16* gb0 = pwt + (size_t)(n0 + wave * 32 + srow) * DIMD + scol;
    const f16* gb1 = pwt + (size_t)(n0 + wave * 32 + 16 + srow) * DIMD + scol;
    f16* la0 = As + (wave * 2) * 512;
    f16* la1 = As + (wave * 2 + 1) * 512;
    f16* lb0 = Bs + (wave * 2) * 512;
    f16* lb1 = Bs + (wave * 2 + 1) * 512;
    v4f acc[4][4] = {};
    for (int k0 = 0; k0 < DIMD; k0 += 32) {
        async_cp16(ga0 + k0, la0);
        async_cp16(ga1 + k0, la1);
        async_cp16(gb0 + k0, lb0);
        async_cp16(gb1 + k0, lb1);
        __syncthreads();
        v8h a[4], b[4];
#pragma unroll
        for (int i = 0; i < 4; ++i) a[i] = *(const v8h*)(As + (wm + i * 16 + l15) * 32 + quad * 8);
#pragma unroll
        for (int j = 0; j < 4; ++j) b[j] = *(const v8h*)(Bs + (wn + j * 16 + l15) * 32 + quad * 8);
#pragma unroll
        for (int i = 0; i < 4; ++i)
#pragma unroll
            for (int j = 0; j < 4; ++j)
                acc[i][j] = __builtin_amdgcn_mfma_f32_16x16x32_f16(a[i], b[j], acc[i][j], 0, 0, 0);
        __syncthreads();
    }
#pragma unroll
    for (int i = 0; i < 4; ++i)
#pragma unroll
        for (int e = 0; e < 4; ++e) {
            int gm = m0 + wm + i * 16 + quad * 4 + e;
            if (gm < NTOK) {
#pragma unroll
                for (int j = 0; j < 4; ++j) {
                    int gn = n0 + wn + j * 16 + l15;
                    out[(size_t)gm * DIMD + gn] = acc[i][j][e] + pb[gn];
                }
            }
        }
}

extern "C" void kernel_launch(void* const* d_in, const int* in_sizes, int n_in,
                              void* d_out, int out_size, void* d_ws, size_t ws_size,
                              hipStream_t stream) {
    const float* x      = (const float*)d_in[0];
    const float* qkv_w  = (const float*)d_in[1];
    const float* table  = (const float*)d_in[2];
    const float* proj_w = (const float*)d_in[3];
    const float* proj_b = (const float*)d_in[4];
    const int* mask     = (const int*)d_in[5];
    const int* rel      = (const int*)d_in[6];
    float* out = (float*)d_out;
    char* ws = (char*)d_ws;

    f16* q    = (f16*)(ws + OFF_Q);
    f16* k    = (f16*)(ws + OFF_K);
    f16* v    = (f16*)(ws + OFF_V);
    f16* xh   = (f16*)(ws + OFF_AO);   // xh and ao share the [MP][384] buffer
    f16* ao   = (f16*)(ws + OFF_AO);
    float* bt = (float*)(ws + OFF_BT);
    f16* wt   = (f16*)(ws + OFF_WT);
    f16* pwt  = (f16*)(ws + OFF_PWT);
    unsigned int* mtb = (unsigned int*)(ws + OFF_MTB);

    (void)hipFuncSetAttribute((const void*)attn_kernel,
                              hipFuncAttributeMaxDynamicSharedMemorySize, SMEM_ATTN);

    prep_all<<<(SPREP + 255) / 256, 256, 0, stream>>>(
        x, xh, qkv_w, wt, proj_w, pwt, table, rel, bt, mask, mtb);
    qkv_gemm<<<dim3(MPT * 9), 256, 0, stream>>>(xh, wt, q, k, v);
    attn_kernel<<<dim3(NWW * NHH), 512, SMEM_ATTN, stream>>>(q, k, v, bt, mtb, ao);
    proj_gemm<<<dim3(MPT * 3), 256, 0, stream>>>(ao, pwt, proj_b, out);
}